// Round 11
// baseline (858.238 us; speedup 1.0000x reference)
//
#include <hip/hip_runtime.h>
#include <hip/hip_bf16.h>
#include <math.h>

#define N_CAND 524288
#define RB     128
#define NBLK   (N_CAND / RB)     // 4096 tiles
#define GRIDM  256               // persistent, 1 block/CU (LDS-limited)
#define TPB    (NBLK / GRIDM)    // 16 tiles per block
#define EMB    128
#define HID    256
#define BGR    2048

#define OUT_XS  262144                      // offset of X_states in out (floats)
#define OUT_P   (262144 + 134217728)        // offset of probs in out (floats)

typedef __attribute__((ext_vector_type(4))) float f32x4;
typedef __attribute__((ext_vector_type(8))) short bf16x8;
typedef __attribute__((ext_vector_type(4))) short bf16x4;
typedef unsigned short u16;

// Native convert (RNE): pairs compile to v_cvt_pk_bf16_f32.
__device__ __forceinline__ u16 f2bf(float f) {
  __hip_bfloat16 h = __float2bfloat16(f);
  return *reinterpret_cast<u16*>(&h);
}

// Raw barrier: waits LDS ops only (lgkmcnt), does NOT drain vmcnt.
// Global stores (X_states) and in-flight prefetch loads keep flowing.
__device__ __forceinline__ void bar_lgkm() {
  __builtin_amdgcn_sched_barrier(0);
  asm volatile("s_waitcnt lgkmcnt(0)" ::: "memory");
  __builtin_amdgcn_sched_barrier(0);
  __builtin_amdgcn_s_barrier();
  __builtin_amdgcn_sched_barrier(0);
}
__device__ __forceinline__ void bar_only() {
  __builtin_amdgcn_sched_barrier(0);
  __builtin_amdgcn_s_barrier();
  __builtin_amdgcn_sched_barrier(0);
}

// ---- K0: W1/W2/W3 (f32, [k][n]) -> MFMA-fragment-packed bf16 ----
// dst u16 index = ((L*16+nt)*8+ks)*512 + lane*8 + j  (lane = g*16+ml).
// A wave's A-fragment load (nt,ks) is 64 lanes x 16B = 1 KB contiguous.
__global__ void k_prep(const float* __restrict__ W1, const float* __restrict__ W2,
                       const float* __restrict__ W3, u16* __restrict__ wt) {
  const int b = blockIdx.x;
  const int m = b >> 8;          // which matrix
  const int n = b & 255;         // output unit
  const int k = threadIdx.x;     // input unit
  const float* W = (m == 0) ? W1 : ((m == 1) ? W2 : W3);
  const int nt = n >> 4, ml = n & 15;
  const int ks = k >> 5, g = (k >> 3) & 3, j = k & 7;
  const int lane = g * 16 + ml;
  wt[(((m * 16 + nt) * 8 + ks) << 9) + lane * 8 + j] = f2bf(W[k * 256 + n]);
}

// Consumer K-loop: wave computes 64n x 128r, acc[4][8] = 128 AGPR.
__device__ __forceinline__ void mfma_k(const char* wl, const char* hbr, int bofs,
                                       f32x4 (&acc)[4][8])
{
  #pragma unroll
  for (int nf = 0; nf < 4; ++nf)
    #pragma unroll
    for (int rf = 0; rf < 8; ++rf)
      acc[nf][rf] = (f32x4){0.f, 0.f, 0.f, 0.f};

  __builtin_amdgcn_s_setprio(1);
  #pragma unroll
  for (int ks = 0; ks < 8; ++ks) {
    bf16x8 a[4];
    #pragma unroll
    for (int af = 0; af < 4; ++af)
      a[af] = *(const bf16x8*)(wl + (af * 8 + ks) * 1024);   // 1KB coalesced (L2)
    #pragma unroll
    for (int rh = 0; rh < 2; ++rh) {
      bf16x8 bq[4];
      #pragma unroll
      for (int rj = 0; rj < 4; ++rj)
        bq[rj] = *(const bf16x8*)(hbr + (rh * 4 + rj) * 8192 + ((ks * 64) ^ bofs));
      #pragma unroll
      for (int af = 0; af < 4; ++af)
        #pragma unroll
        for (int rj = 0; rj < 4; ++rj)
          acc[af][rh * 4 + rj] = __builtin_amdgcn_mfma_f32_16x16x32_bf16(
              a[af], bq[rj], acc[af][rh * 4 + rj], 0, 0, 0);
    }
  }
  __builtin_amdgcn_s_setprio(0);
}

// Consumer epilogue (layers 1,2): +bias, relu, ->bf16, in-place swizzled write.
__device__ __forceinline__ void epi(const float* bs, char* hb, int wn0, int g,
                                    int ml, int swz, const f32x4 (&acc)[4][8])
{
  #pragma unroll
  for (int nf = 0; nf < 4; ++nf) {
    const int n0 = wn0 + nf * 16 + g * 4;
    const f32x4 bb = *(const f32x4*)(bs + n0);
    #pragma unroll
    for (int rf = 0; rf < 8; ++rf) {
      const int r = rf * 16 + ml;
      bf16x4 hv;
      #pragma unroll
      for (int q = 0; q < 4; ++q) {
        float x = acc[nf][rf][q] + bb[q];
        x = fmaxf(x, 0.f);
        hv[q] = (short)f2bf(x);
      }
      *(bf16x4*)(hb + r * 512 + ((n0 * 2) ^ swz)) = hv;
    }
  }
}

// ---- K1: producer/consumer persistent pipeline ----
// 8 waves: waves 0-3 = consumers (3-layer MFMA MLP + fused head on cur),
// waves 4-7 = producers (stream tile t+1 into nxt: global loads issued in
// t-1's L3 window, drained + X_states-stored + ds_written in t's L1 window).
// Barriers are wave-uniform; lgkm-only (stores never drained at a barrier).
__global__ __launch_bounds__(512, 2) void k_main(
    const float* __restrict__ g_emb, const float* __restrict__ cand,
    const int* __restrict__ bidx,
    const float* __restrict__ b1, const float* __restrict__ b2,
    const float* __restrict__ b3, const float* __restrict__ Wf,
    const float* __restrict__ bfp, const u16* __restrict__ wt,
    float* __restrict__ out)
{
  __shared__ __align__(16) u16 bufA[RB * HID];   // 64 KB
  __shared__ __align__(16) u16 bufB[RB * HID];   // 64 KB
  __shared__ float bias_s[3 * HID];
  __shared__ float bf_s;

  const int tid  = threadIdx.x;
  const int wid  = tid >> 6;
  const bool cons = (wid < 4);
  const int t0   = blockIdx.x * TPB;

  if (tid < HID) {
    bias_s[tid]           = b1[tid];
    bias_s[HID + tid]     = b2[tid];
    bias_s[2 * HID + tid] = b3[tid];
    if (tid == 0) bf_s = bfp[0];
  }

  // consumer constants
  const int lane = tid & 63;
  const int ml   = lane & 15;
  const int g    = lane >> 4;
  const int w    = wid;            // 0..3 for consumers
  const int wn0  = w * 64;
  const int swz  = ml << 4;
  const int bofs = (g * 16) ^ swz;

  // producer constants
  const int ptid  = tid & 255;     // 0..255 for producer waves
  const int kc    = ptid & 31;     // 16B chunk within 256-col row
  const int prow0 = ptid >> 5;     // 0..7 -> rows prow0 + i*8

  u16* cur = bufA;
  u16* nxt = bufB;

  // producer-held state (dead on consumer path)
  f32x4 ld0[16], ld1[16];
  int   bpre[16];

  // ---- prologue: producers stage tile t0 into bufA, issue loads for t0+1 ----
  if (!cons) {
    {
      const int r0 = t0 * RB;
      #pragma unroll
      for (int i = 0; i < 16; ++i) bpre[i] = bidx[r0 + prow0 + i * 8];
      #pragma unroll
      for (int i = 0; i < 16; ++i) {
        const int row = prow0 + i * 8;
        const int r   = r0 + row;
        const float* src = (kc < 16)
            ? g_emb + (size_t)bpre[i] * EMB + kc * 8
            : cand  + (size_t)r * EMB + (kc - 16) * 8;
        ld0[i] = *(const f32x4*)src;
        ld1[i] = *(const f32x4*)(src + 4);
      }
      char* l0 = (char*)cur;
      #pragma unroll
      for (int i = 0; i < 16; ++i) {
        const int row = prow0 + i * 8;
        const int r   = r0 + row;
        float* dst = out + OUT_XS + (size_t)r * (2 * EMB) + kc * 8;
        *(f32x4*)dst       = ld0[i];
        *(f32x4*)(dst + 4) = ld1[i];
        bf16x8 hv;
        hv[0] = (short)f2bf(ld0[i].x); hv[1] = (short)f2bf(ld0[i].y);
        hv[2] = (short)f2bf(ld0[i].z); hv[3] = (short)f2bf(ld0[i].w);
        hv[4] = (short)f2bf(ld1[i].x); hv[5] = (short)f2bf(ld1[i].y);
        hv[6] = (short)f2bf(ld1[i].z); hv[7] = (short)f2bf(ld1[i].w);
        *(bf16x8*)(l0 + row * 512 + ((kc * 16) ^ ((row & 15) << 4))) = hv;
      }
    }
    { // issue loads for tile t0+1 (held in regs; drained next L1 window)
      const int r0 = (t0 + 1) * RB;
      #pragma unroll
      for (int i = 0; i < 16; ++i) bpre[i] = bidx[r0 + prow0 + i * 8];
      #pragma unroll
      for (int i = 0; i < 16; ++i) {
        const int row = prow0 + i * 8;
        const int r   = r0 + row;
        const float* src = (kc < 16)
            ? g_emb + (size_t)bpre[i] * EMB + kc * 8
            : cand  + (size_t)r * EMB + (kc - 16) * 8;
        ld0[i] = *(const f32x4*)src;
        ld1[i] = *(const f32x4*)(src + 4);
      }
    }
  }
  bar_lgkm();

  #pragma unroll 1
  for (int t = 0; t < TPB; ++t) {
    char* const hb  = (char*)cur;
    const char* const hbr = hb + (size_t)ml * 512;

    f32x4 acc[4][8];

    // ---- L1 window: consumers MFMA(cur) | producers drain+stage nxt ----
    if (cons) {
      mfma_k((const char*)wt + (size_t)((0 * 16 + w * 4) * 8) * 1024 + lane * 16,
             hbr, bofs, acc);
    } else if (t + 1 < TPB) {
      const int r0 = (t0 + t + 1) * RB;
      char* l0 = (char*)nxt;
      #pragma unroll
      for (int i = 0; i < 16; ++i) {
        const int row = prow0 + i * 8;
        const int r   = r0 + row;
        float* dst = out + OUT_XS + (size_t)r * (2 * EMB) + kc * 8;
        *(f32x4*)dst       = ld0[i];   // fire-and-forget
        *(f32x4*)(dst + 4) = ld1[i];
        bf16x8 hv;
        hv[0] = (short)f2bf(ld0[i].x); hv[1] = (short)f2bf(ld0[i].y);
        hv[2] = (short)f2bf(ld0[i].z); hv[3] = (short)f2bf(ld0[i].w);
        hv[4] = (short)f2bf(ld1[i].x); hv[5] = (short)f2bf(ld1[i].y);
        hv[6] = (short)f2bf(ld1[i].z); hv[7] = (short)f2bf(ld1[i].w);
        *(bf16x8*)(l0 + row * 512 + ((kc * 16) ^ ((row & 15) << 4))) = hv;
      }
    }
    bar_only();
    if (cons) epi(bias_s, hb, wn0, g, ml, swz, acc);
    bar_lgkm();

    // ---- L2 window ----
    if (cons)
      mfma_k((const char*)wt + (size_t)((1 * 16 + w * 4) * 8) * 1024 + lane * 16,
             hbr, bofs, acc);
    bar_only();
    if (cons) epi(bias_s + HID, hb, wn0, g, ml, swz, acc);
    bar_lgkm();

    // ---- L3 window: consumers MFMA | producers issue loads for t+2 ----
    if (cons) {
      mfma_k((const char*)wt + (size_t)((2 * 16 + w * 4) * 8) * 1024 + lane * 16,
             hbr, bofs, acc);
    } else if (t + 2 < TPB) {
      const int r0 = (t0 + t + 2) * RB;
      #pragma unroll
      for (int i = 0; i < 16; ++i) bpre[i] = bidx[r0 + prow0 + i * 8];
      #pragma unroll
      for (int i = 0; i < 16; ++i) {
        const int row = prow0 + i * 8;
        const int r   = r0 + row;
        const float* src = (kc < 16)
            ? g_emb + (size_t)bpre[i] * EMB + kc * 8
            : cand  + (size_t)r * EMB + (kc - 16) * 8;
        ld0[i] = *(const f32x4*)src;
        ld1[i] = *(const f32x4*)(src + 4);
      }
    }
    bar_only();
    if (cons) {
      // fused head epilogue: partials into pad carved from cur
      const float* bs = bias_s + 2 * HID;
      f32x4 bb[4], wfv[4];
      #pragma unroll
      for (int nf = 0; nf < 4; ++nf) {
        bb[nf]  = *(const f32x4*)(bs + wn0 + nf * 16 + g * 4);
        wfv[nf] = *(const f32x4*)(Wf + wn0 + nf * 16 + g * 4);
      }
      float* pad = (float*)cur;   // [128][16] f32, slot-swizzled
      #pragma unroll
      for (int rf = 0; rf < 8; ++rf) {
        const int r = rf * 16 + ml;
        float p = 0.f;
        #pragma unroll
        for (int nf = 0; nf < 4; ++nf) {
          f32x4 x = acc[nf][rf] + bb[nf];
          #pragma unroll
          for (int q = 0; q < 4; ++q)
            p += fmaxf(x[q], 0.f) * wfv[nf][q];
        }
        const int slot = (w * 4 + g) ^ ((r & 3) << 2);
        pad[r * 16 + slot] = p;
      }
    }
    bar_lgkm();
    if (cons) {
      // reduce 16 partials/row -> e = exp(logit)
      const int row  = tid >> 1;   // 0..127
      const int part = tid & 1;
      const int sx   = (row & 3) << 2;
      const float* pad = (const float*)cur;
      f32x4 v0 = *(const f32x4*)(pad + row * 16 + ((part * 8) ^ sx));
      f32x4 v1 = *(const f32x4*)(pad + row * 16 + ((part * 8 + 4) ^ sx));
      float s = v0[0] + v0[1] + v0[2] + v0[3] + v1[0] + v1[1] + v1[2] + v1[3];
      s += __shfl_xor(s, 1);
      if (part == 0)
        out[OUT_P + (size_t)((t0 + t) * RB + row)] = __expf(s + bf_s);
    }
    bar_only();   // boundary: pad reads done; nxt fully staged (at L1 bar)

    u16* tmp = cur; cur = nxt; nxt = tmp;
  }
}

// ---- K2: fused segment softmax-denominator + divide + g_emb copy ----
// Block b: binary-search segment [lo,hi) of graph b in sorted bidx,
// sum e, then probs = e/denom in place; also copies g_emb row b.
__global__ __launch_bounds__(256) void k_soft(
    const float* __restrict__ g_emb, const int* __restrict__ bidx,
    float* __restrict__ out)
{
  const int b   = blockIdx.x;
  const int tid = threadIdx.x;
  __shared__ float ws[4];
  __shared__ float sden;

  int lo = 0, hi = N_CAND;
  while (lo < hi) { int m = (lo + hi) >> 1; if (bidx[m] < b) lo = m + 1; else hi = m; }
  int lo2 = lo, hi2 = N_CAND;
  while (lo2 < hi2) { int m = (lo2 + hi2) >> 1; if (bidx[m] < b + 1) lo2 = m + 1; else hi2 = m; }

  float s = 0.f;
  for (int i = lo + tid; i < lo2; i += 256) s += out[OUT_P + (size_t)i];
  #pragma unroll
  for (int off = 32; off > 0; off >>= 1) s += __shfl_down(s, off);
  if ((tid & 63) == 0) ws[tid >> 6] = s;
  __syncthreads();
  if (tid == 0) sden = ws[0] + ws[1] + ws[2] + ws[3];
  __syncthreads();
  const float d = sden;
  for (int i = lo + tid; i < lo2; i += 256)
    out[OUT_P + (size_t)i] = out[OUT_P + (size_t)i] / d;

  if (tid < 32) {
    f32x4 v = *(const f32x4*)(g_emb + (size_t)b * EMB + tid * 4);
    *(f32x4*)(out + (size_t)b * EMB + tid * 4) = v;
  }
}

extern "C" void kernel_launch(void* const* d_in, const int* in_sizes, int n_in,
                              void* d_out, int out_size, void* d_ws, size_t ws_size,
                              hipStream_t stream)
{
  const float* g_emb = (const float*)d_in[0];
  const float* cand  = (const float*)d_in[1];
  const float* W1    = (const float*)d_in[2];
  const float* b1    = (const float*)d_in[3];
  const float* W2    = (const float*)d_in[4];
  const float* b2    = (const float*)d_in[5];
  const float* W3    = (const float*)d_in[6];
  const float* b3    = (const float*)d_in[7];
  const float* Wf    = (const float*)d_in[8];
  const float* bfp   = (const float*)d_in[9];
  const int*   bidx  = (const int*)d_in[10];
  float* out = (float*)d_out;

  u16* wt = (u16*)d_ws;    // 3 * 128 KB packed bf16 weights

  k_prep <<<768, 256, 0, stream>>>(W1, W2, W3, wt);
  k_main <<<GRIDM, 512, 0, stream>>>(g_emb, cand, bidx, b1, b2, b3, Wf, bfp, wt, out);
  k_soft <<<BGR, 256, 0, stream>>>(g_emb, bidx, out);
}

// Round 12
// 478.368 us; speedup vs baseline: 1.7941x; 1.7941x over previous
//
#include <hip/hip_runtime.h>
#include <hip/hip_bf16.h>
#include <math.h>

#define N_CAND 524288
#define RB     128
#define NBLK   (N_CAND / RB)     // 4096
#define EMB    128
#define HID    256
#define BGR    2048

#define OUT_XS  262144                      // offset of X_states in out (floats)
#define OUT_P   (262144 + 134217728)        // offset of probs in out (floats)

typedef __attribute__((ext_vector_type(4))) float f32x4;
typedef __attribute__((ext_vector_type(8))) short bf16x8;
typedef __attribute__((ext_vector_type(4))) short bf16x4;
typedef unsigned short u16;

// Native convert (RNE): pairs compile to v_cvt_pk_bf16_f32.
__device__ __forceinline__ u16 f2bf(float f) {
  __hip_bfloat16 h = __float2bfloat16(f);
  return *reinterpret_cast<u16*>(&h);
}

// Raw barrier: waits LDS ops only (lgkmcnt), does NOT drain vmcnt.
// Global stores (X_states) keep flowing under later phases.
__device__ __forceinline__ void bar_lgkm() {
  __builtin_amdgcn_sched_barrier(0);
  asm volatile("s_waitcnt lgkmcnt(0)" ::: "memory");
  __builtin_amdgcn_sched_barrier(0);
  __builtin_amdgcn_s_barrier();
  __builtin_amdgcn_sched_barrier(0);
}
__device__ __forceinline__ void bar_only() {
  __builtin_amdgcn_sched_barrier(0);
  __builtin_amdgcn_s_barrier();
  __builtin_amdgcn_sched_barrier(0);
}

// ---- K0: W1/W2/W3 (f32, [k][n]) -> MFMA-fragment-packed bf16 ----
// dst u16 index = ((L*16+nt)*8+ks)*512 + lane*8 + j  (lane = g*16+ml).
// A wave's A-fragment load (nt,ks) is 64 lanes x 16B = 1 KB contiguous.
__global__ void k_prep(const float* __restrict__ W1, const float* __restrict__ W2,
                       const float* __restrict__ W3, u16* __restrict__ wt) {
  const int b = blockIdx.x;
  const int m = b >> 8;          // which matrix
  const int n = b & 255;         // output unit
  const int k = threadIdx.x;     // input unit
  const float* W = (m == 0) ? W1 : ((m == 1) ? W2 : W3);
  const int nt = n >> 4, ml = n & 15;
  const int ks = k >> 5, g = (k >> 3) & 3, j = k & 7;
  const int lane = g * 16 + ml;
  wt[(((m * 16 + nt) * 8 + ks) << 9) + lane * 8 + j] = f2bf(W[k * 256 + n]);
}

// Consumer K-loop (r10 geometry): wave owns 32n x 128r, acc[2][8] = 64 AGPR.
// acc initialized from the bias fragment (free bias via MFMA C-in).
__device__ __forceinline__ void mfma_k(const char* wl, const char* hbr, int bofs,
                                       const float* bs, int wn0, int g,
                                       f32x4 (&acc)[2][8])
{
  #pragma unroll
  for (int nf = 0; nf < 2; ++nf) {
    const f32x4 bb = *(const f32x4*)(bs + wn0 + nf * 16 + g * 4);
    #pragma unroll
    for (int rf = 0; rf < 8; ++rf)
      acc[nf][rf] = bb;
  }

  __builtin_amdgcn_s_setprio(1);
  #pragma unroll
  for (int ks = 0; ks < 8; ++ks) {
    bf16x8 a[2];
    #pragma unroll
    for (int nf = 0; nf < 2; ++nf)
      a[nf] = *(const bf16x8*)(wl + (nf * 8 + ks) * 1024);   // 1KB coalesced (L2)
    #pragma unroll
    for (int rh = 0; rh < 2; ++rh) {
      bf16x8 bq[4];
      #pragma unroll
      for (int rj = 0; rj < 4; ++rj)
        bq[rj] = *(const bf16x8*)(hbr + (rh * 4 + rj) * 8192 + ((ks * 64) ^ bofs));
      #pragma unroll
      for (int nf = 0; nf < 2; ++nf)
        #pragma unroll
        for (int rj = 0; rj < 4; ++rj)
          acc[nf][rh * 4 + rj] = __builtin_amdgcn_mfma_f32_16x16x32_bf16(
              a[nf], bq[rj], acc[nf][rh * 4 + rj], 0, 0, 0);
    }
  }
  __builtin_amdgcn_s_setprio(0);
}

// Epilogue (layers 1,2): relu, ->bf16, in-place swizzled write (bias pre-added).
__device__ __forceinline__ void epi(char* hb, int wn0, int g, int ml, int swz,
                                    const f32x4 (&acc)[2][8])
{
  #pragma unroll
  for (int nf = 0; nf < 2; ++nf) {
    const int n0 = wn0 + nf * 16 + g * 4;
    #pragma unroll
    for (int rf = 0; rf < 8; ++rf) {
      const int r = rf * 16 + ml;
      bf16x4 hv;
      #pragma unroll
      for (int q = 0; q < 4; ++q)
        hv[q] = (short)f2bf(fmaxf(acc[nf][rf][q], 0.f));
      *(bf16x4*)(hb + r * 512 + ((n0 * 2) ^ swz)) = hv;
    }
  }
}

// ---- K1: fused X-concat + 3-layer MLP + fused head ----
// r10 champion structure (8 waves, RB=128, weights once/block, 2 blocks/CU).
// Changes: stage = load+cvt+ds_write only; the X_states f32 stores happen
// inside layer-1's MFMA window by re-loading the (L2-hot) tile and storing
// fire-and-forget -> HBM write burst spreads under compute. Bias via acc-init.
__global__ __launch_bounds__(512, 4) void k_main(
    const float* __restrict__ g_emb, const float* __restrict__ cand,
    const int* __restrict__ bidx,
    const float* __restrict__ b1, const float* __restrict__ b2,
    const float* __restrict__ b3, const float* __restrict__ Wf,
    const float* __restrict__ bfp, const u16* __restrict__ wt,
    float* __restrict__ out)
{
  __shared__ __align__(16) u16 hbuf[RB * HID];   // 64 KB, chunk-XOR swizzled
  __shared__ float bias_s[3 * HID];
  __shared__ float bf_s;

  const int tid = threadIdx.x;
  const int r0  = blockIdx.x * RB;

  if (tid < HID) {
    bias_s[tid]           = b1[tid];
    bias_s[HID + tid]     = b2[tid];
    bias_s[2 * HID + tid] = b3[tid];
    if (tid == 0) bf_s = bfp[0];
  }

  const int kc   = tid & 31;    // 16B chunk (8 elems) within the 256-col row
  const int row0 = tid >> 5;    // 0..15

  // ---- stage X (concat) into LDS bf16 swizzled (NO global stores here) ----
  int bpre[8];
  {
    char* l0 = (char*)hbuf;
    #pragma unroll
    for (int i = 0; i < 8; ++i)
      bpre[i] = bidx[r0 + row0 + i * 16];   // break dependent-load chain
    #pragma unroll
    for (int i = 0; i < 8; ++i) {
      const int row = row0 + i * 16;        // 0..127
      const int r   = r0 + row;
      const float* src = (kc < 16)
          ? g_emb + (size_t)bpre[i] * EMB + kc * 8
          : cand  + (size_t)r * EMB + (kc - 16) * 8;
      f32x4 v0 = *(const f32x4*)(src);
      f32x4 v1 = *(const f32x4*)(src + 4);
      bf16x8 hv;
      hv[0] = (short)f2bf(v0.x); hv[1] = (short)f2bf(v0.y);
      hv[2] = (short)f2bf(v0.z); hv[3] = (short)f2bf(v0.w);
      hv[4] = (short)f2bf(v1.x); hv[5] = (short)f2bf(v1.y);
      hv[6] = (short)f2bf(v1.z); hv[7] = (short)f2bf(v1.w);
      *(bf16x8*)(l0 + row * 512 + ((kc * 16) ^ ((row & 15) << 4))) = hv;
    }
  }
  bar_lgkm();

  const int lane = tid & 63;
  const int w    = tid >> 6;          // 0..7
  const int ml   = lane & 15;
  const int g    = lane >> 4;         // 0..3
  const int wn0  = w * 32;            // n-offset: 2 tiles of 16 per wave

  const int swz  = ml << 4;                 // row-swizzle ((rf*16+ml)&15 == ml)
  const int bofs = (g * 16) ^ swz;          // k-chunk xor per lane
  char* const hb  = (char*)hbuf;
  const char* const hbr = hb + (size_t)ml * 512;  // B-read base

  f32x4 acc[2][8];

  // ---- layer 1 window: MFMA + X_states store interleave ----
  mfma_k((const char*)wt + (size_t)((0 * 16 + w * 2) * 8) * 1024 + lane * 16,
         hbr, bofs, bias_s, wn0, g, acc);
  {
    // re-load tile f32 (L2-hot) and store X_states; fire-and-forget,
    // drains under the following windows (lgkm-only barriers).
    #pragma unroll
    for (int i = 0; i < 8; ++i) {
      const int row = row0 + i * 16;
      const int r   = r0 + row;
      const float* src = (kc < 16)
          ? g_emb + (size_t)bpre[i] * EMB + kc * 8
          : cand  + (size_t)r * EMB + (kc - 16) * 8;
      f32x4 v0 = *(const f32x4*)(src);
      f32x4 v1 = *(const f32x4*)(src + 4);
      float* dst = out + OUT_XS + (size_t)r * (2 * EMB) + kc * 8;
      *(f32x4*)dst       = v0;
      *(f32x4*)(dst + 4) = v1;
    }
  }
  bar_only();
  epi(hb, wn0, g, ml, swz, acc);
  bar_lgkm();

  // ---- layer 2 window ----
  mfma_k((const char*)wt + (size_t)((1 * 16 + w * 2) * 8) * 1024 + lane * 16,
         hbr, bofs, bias_s + HID, wn0, g, acc);
  bar_only();
  epi(hb, wn0, g, ml, swz, acc);
  bar_lgkm();

  // ---- layer 3 + head, fused: h3 stays in registers ----
  mfma_k((const char*)wt + (size_t)((2 * 16 + w * 2) * 8) * 1024 + lane * 16,
         hbr, bofs, bias_s + 2 * HID, wn0, g, acc);
  bar_only();   // all h2 reads done -> hbuf reusable as reduction pad
  {
    const f32x4 wf0 = *(const f32x4*)(Wf + wn0 + g * 4);
    const f32x4 wf1 = *(const f32x4*)(Wf + wn0 + 16 + g * 4);

    float* pad = (float*)hbuf;   // [128][32] f32 partials, slot-swizzled
    #pragma unroll
    for (int rf = 0; rf < 8; ++rf) {
      const int r = rf * 16 + ml;
      float p = 0.f;
      #pragma unroll
      for (int q = 0; q < 4; ++q) {
        p += fmaxf(acc[0][rf][q], 0.f) * wf0[q];
        p += fmaxf(acc[1][rf][q], 0.f) * wf1[q];
      }
      const int slot = (w * 4 + g) ^ ((r & 7) << 2);   // conflict-free banks
      pad[r * 32 + slot] = p;
    }
    bar_lgkm();

    // reduce: 4 threads per row sum 32 partials -> e = exp(logit)
    {
      const int row  = tid >> 2;   // 0..127
      const int part = tid & 3;
      const int sx   = (row & 7) << 2;
      f32x4 v0 = *(const f32x4*)(pad + row * 32 + ((part * 8) ^ sx));
      f32x4 v1 = *(const f32x4*)(pad + row * 32 + ((part * 8 + 4) ^ sx));
      float s = v0[0] + v0[1] + v0[2] + v0[3] + v1[0] + v1[1] + v1[2] + v1[3];
      s += __shfl_xor(s, 1);
      s += __shfl_xor(s, 2);
      if (part == 0)
        out[OUT_P + (size_t)(r0 + row)] = __expf(s + bf_s);
    }
  }
}

// ---- K2: fused segment softmax-denominator + divide + g_emb copy ----
__global__ __launch_bounds__(256) void k_soft(
    const float* __restrict__ g_emb, const int* __restrict__ bidx,
    float* __restrict__ out)
{
  const int b   = blockIdx.x;
  const int tid = threadIdx.x;
  __shared__ float ws[4];
  __shared__ float sden;

  int lo = 0, hi = N_CAND;
  while (lo < hi) { int m = (lo + hi) >> 1; if (bidx[m] < b) lo = m + 1; else hi = m; }
  int lo2 = lo, hi2 = N_CAND;
  while (lo2 < hi2) { int m = (lo2 + hi2) >> 1; if (bidx[m] < b + 1) lo2 = m + 1; else hi2 = m; }

  float s = 0.f;
  for (int i = lo + tid; i < lo2; i += 256) s += out[OUT_P + (size_t)i];
  #pragma unroll
  for (int off = 32; off > 0; off >>= 1) s += __shfl_down(s, off);
  if ((tid & 63) == 0) ws[tid >> 6] = s;
  __syncthreads();
  if (tid == 0) sden = ws[0] + ws[1] + ws[2] + ws[3];
  __syncthreads();
  const float d = sden;
  for (int i = lo + tid; i < lo2; i += 256)
    out[OUT_P + (size_t)i] = out[OUT_P + (size_t)i] / d;

  if (tid < 32) {
    f32x4 v = *(const f32x4*)(g_emb + (size_t)b * EMB + tid * 4);
    *(f32x4*)(out + (size_t)b * EMB + tid * 4) = v;
  }
}

extern "C" void kernel_launch(void* const* d_in, const int* in_sizes, int n_in,
                              void* d_out, int out_size, void* d_ws, size_t ws_size,
                              hipStream_t stream)
{
  const float* g_emb = (const float*)d_in[0];
  const float* cand  = (const float*)d_in[1];
  const float* W1    = (const float*)d_in[2];
  const float* b1    = (const float*)d_in[3];
  const float* W2    = (const float*)d_in[4];
  const float* b2    = (const float*)d_in[5];
  const float* W3    = (const float*)d_in[6];
  const float* b3    = (const float*)d_in[7];
  const float* Wf    = (const float*)d_in[8];
  const float* bfp   = (const float*)d_in[9];
  const int*   bidx  = (const int*)d_in[10];
  float* out = (float*)d_out;

  u16* wt = (u16*)d_ws;    // 3 * 128 KB packed bf16 weights

  k_prep <<<768, 256, 0, stream>>>(W1, W2, W3, wt);
  k_main <<<NBLK, 512, 0, stream>>>(g_emb, cand, bidx, b1, b2, b3, Wf, bfp, wt, out);
  k_soft <<<BGR, 256, 0, stream>>>(g_emb, bidx, out);
}

// Round 13
// 393.963 us; speedup vs baseline: 2.1785x; 1.2142x over previous
//
#include <hip/hip_runtime.h>
#include <hip/hip_bf16.h>
#include <math.h>

#define N_CAND 524288
#define RB     128
#define NBLK   (N_CAND / RB)     // 4096
#define EMB    128
#define HID    256
#define BGR    2048

#define OUT_XS  262144                      // offset of X_states in out (floats)
#define OUT_P   (262144 + 134217728)        // offset of probs in out (floats)

typedef __attribute__((ext_vector_type(4))) float f32x4;
typedef __attribute__((ext_vector_type(8))) short bf16x8;
typedef __attribute__((ext_vector_type(4))) short bf16x4;
typedef unsigned short u16;

// Native convert (RNE): pairs compile to v_cvt_pk_bf16_f32.
__device__ __forceinline__ u16 f2bf(float f) {
  __hip_bfloat16 h = __float2bfloat16(f);
  return *reinterpret_cast<u16*>(&h);
}

// Raw barrier: waits LDS ops only (lgkmcnt), does NOT drain vmcnt.
// Global stores (X_states) keep flowing under later phases.
__device__ __forceinline__ void bar_lgkm() {
  __builtin_amdgcn_sched_barrier(0);
  asm volatile("s_waitcnt lgkmcnt(0)" ::: "memory");
  __builtin_amdgcn_sched_barrier(0);
  __builtin_amdgcn_s_barrier();
  __builtin_amdgcn_sched_barrier(0);
}
__device__ __forceinline__ void bar_only() {
  __builtin_amdgcn_sched_barrier(0);
  __builtin_amdgcn_s_barrier();
  __builtin_amdgcn_sched_barrier(0);
}

// ---- K0: W1/W2/W3 (f32, [k][n]) -> MFMA-fragment-packed bf16 ----
// dst u16 index = ((L*16+nt)*8+ks)*512 + lane*8 + j  (lane = g*16+ml).
// A wave's A-fragment load (nt,ks) is 64 lanes x 16B = 1 KB contiguous.
__global__ void k_prep(const float* __restrict__ W1, const float* __restrict__ W2,
                       const float* __restrict__ W3, u16* __restrict__ wt) {
  const int b = blockIdx.x;
  const int m = b >> 8;          // which matrix
  const int n = b & 255;         // output unit
  const int k = threadIdx.x;     // input unit
  const float* W = (m == 0) ? W1 : ((m == 1) ? W2 : W3);
  const int nt = n >> 4, ml = n & 15;
  const int ks = k >> 5, g = (k >> 3) & 3, j = k & 7;
  const int lane = g * 16 + ml;
  wt[(((m * 16 + nt) * 8 + ks) << 9) + lane * 8 + j] = f2bf(W[k * 256 + n]);
}

// K-loop, wave grid 4n x 2r: wave owns 64n x 64r, acc[4][4] = 64 AGPR.
// acc initialized from the bias fragment (free bias via MFMA C-in).
// Per ks: 4 packed A-loads (L2) + 4 ds_reads + 16 MFMA (thick cluster).
__device__ __forceinline__ void mfma_k(const char* wl, const char* hbr, int bofs,
                                       const float* bs, int wn0, int g,
                                       f32x4 (&acc)[4][4])
{
  #pragma unroll
  for (int nf = 0; nf < 4; ++nf) {
    const f32x4 bb = *(const f32x4*)(bs + wn0 + nf * 16 + g * 4);
    #pragma unroll
    for (int rf = 0; rf < 4; ++rf)
      acc[nf][rf] = bb;
  }

  __builtin_amdgcn_s_setprio(1);
  #pragma unroll
  for (int ks = 0; ks < 8; ++ks) {
    bf16x8 a[4], bq[4];
    #pragma unroll
    for (int af = 0; af < 4; ++af)
      a[af] = *(const bf16x8*)(wl + (af * 8 + ks) * 1024);   // 1KB coalesced (L2)
    #pragma unroll
    for (int rj = 0; rj < 4; ++rj)
      bq[rj] = *(const bf16x8*)(hbr + rj * 8192 + ((ks * 64) ^ bofs)); // LDS
    #pragma unroll
    for (int af = 0; af < 4; ++af)
      #pragma unroll
      for (int rj = 0; rj < 4; ++rj)
        acc[af][rj] = __builtin_amdgcn_mfma_f32_16x16x32_bf16(
            a[af], bq[rj], acc[af][rj], 0, 0, 0);
  }
  __builtin_amdgcn_s_setprio(0);
}

// Epilogue (layers 1,2): relu, ->bf16, in-place swizzled write (bias pre-added).
__device__ __forceinline__ void epi(char* hb, int wn0, int wr0, int g, int ml,
                                    int swz, const f32x4 (&acc)[4][4])
{
  #pragma unroll
  for (int nf = 0; nf < 4; ++nf) {
    const int n0 = wn0 + nf * 16 + g * 4;
    #pragma unroll
    for (int rf = 0; rf < 4; ++rf) {
      const int r = wr0 + rf * 16 + ml;
      bf16x4 hv;
      #pragma unroll
      for (int q = 0; q < 4; ++q)
        hv[q] = (short)f2bf(fmaxf(acc[nf][rf][q], 0.f));
      *(bf16x4*)(hb + r * 512 + ((n0 * 2) ^ swz)) = hv;
    }
  }
}

// ---- K1: fused X-concat/X_states write + 3-layer MLP + fused head ----
// Champion (r10) structure; wave grid changed 8n x 1r -> 4n x 2r:
// LDS activation traffic halves (6.4 -> 3.2 GB chip-wide), weight L2
// traffic doubles (1.5 -> 3.1 GB) but stays L2-resident (768 KB/XCD).
__global__ __launch_bounds__(512, 4) void k_main(
    const float* __restrict__ g_emb, const float* __restrict__ cand,
    const int* __restrict__ bidx,
    const float* __restrict__ b1, const float* __restrict__ b2,
    const float* __restrict__ b3, const float* __restrict__ Wf,
    const float* __restrict__ bfp, const u16* __restrict__ wt,
    float* __restrict__ out)
{
  __shared__ __align__(16) u16 hbuf[RB * HID];   // 64 KB, chunk-XOR swizzled
  __shared__ float bias_s[3 * HID];
  __shared__ float bf_s;

  const int tid = threadIdx.x;
  const int r0  = blockIdx.x * RB;

  if (tid < HID) {
    bias_s[tid]           = b1[tid];
    bias_s[HID + tid]     = b2[tid];
    bias_s[2 * HID + tid] = b3[tid];
    if (tid == 0) bf_s = bfp[0];
  }

  // ---- stage X (concat) into LDS bf16 swizzled; write X_states f32 ----
  {
    const int kc   = tid & 31;    // 16B chunk (8 elems) within the 256-col row
    const int row0 = tid >> 5;    // 0..15
    char* l0 = (char*)hbuf;
    int bpre[8];
    #pragma unroll
    for (int i = 0; i < 8; ++i)
      bpre[i] = bidx[r0 + row0 + i * 16];   // break dependent-load chain
    #pragma unroll
    for (int i = 0; i < 8; ++i) {
      const int row = row0 + i * 16;        // 0..127
      const int r   = r0 + row;
      const float* src = (kc < 16)
          ? g_emb + (size_t)bpre[i] * EMB + kc * 8
          : cand  + (size_t)r * EMB + (kc - 16) * 8;
      f32x4 v0 = *(const f32x4*)(src);
      f32x4 v1 = *(const f32x4*)(src + 4);
      float* dst = out + OUT_XS + (size_t)r * (2 * EMB) + kc * 8;
      *(f32x4*)dst       = v0;   // async: never waited before a barrier
      *(f32x4*)(dst + 4) = v1;
      bf16x8 hv;
      hv[0] = (short)f2bf(v0.x); hv[1] = (short)f2bf(v0.y);
      hv[2] = (short)f2bf(v0.z); hv[3] = (short)f2bf(v0.w);
      hv[4] = (short)f2bf(v1.x); hv[5] = (short)f2bf(v1.y);
      hv[6] = (short)f2bf(v1.z); hv[7] = (short)f2bf(v1.w);
      *(bf16x8*)(l0 + row * 512 + ((kc * 16) ^ ((row & 15) << 4))) = hv;
    }
  }
  bar_lgkm();

  const int lane = tid & 63;
  const int w    = tid >> 6;          // 0..7
  const int ml   = lane & 15;
  const int g    = lane >> 4;         // 0..3
  const int wn   = w & 3;             // n-stripe 0..3
  const int wr0  = (w >> 2) * 64;     // row-half 0 / 64
  const int wn0  = wn * 64;           // n-offset: 4 tiles of 16

  const int swz  = ml << 4;                 // row-swizzle ((r&15) == ml)
  const int bofs = (g * 16) ^ swz;          // k-chunk xor per lane
  char* const hb  = (char*)hbuf;
  const char* const hbr = hb + (size_t)(wr0 + ml) * 512;  // B-read base

  f32x4 acc[4][4];

  // ---- layers 1,2 ----
  mfma_k((const char*)wt + (size_t)((0 * 16 + wn * 4) * 8) * 1024 + lane * 16,
         hbr, bofs, bias_s, wn0, g, acc);
  bar_only();
  epi(hb, wn0, wr0, g, ml, swz, acc);
  bar_lgkm();

  mfma_k((const char*)wt + (size_t)((1 * 16 + wn * 4) * 8) * 1024 + lane * 16,
         hbr, bofs, bias_s + HID, wn0, g, acc);
  bar_only();
  epi(hb, wn0, wr0, g, ml, swz, acc);
  bar_lgkm();

  // ---- layer 3 + head, fused: h3 stays in registers ----
  mfma_k((const char*)wt + (size_t)((2 * 16 + wn * 4) * 8) * 1024 + lane * 16,
         hbr, bofs, bias_s + 2 * HID, wn0, g, acc);
  bar_only();   // all h2 reads done -> hbuf reusable as reduction pad
  {
    f32x4 wfv[4];
    #pragma unroll
    for (int nf = 0; nf < 4; ++nf)
      wfv[nf] = *(const f32x4*)(Wf + wn0 + nf * 16 + g * 4);

    // pad[128][17] f32: stride-17 -> 16 writer lanes hit 16 distinct banks
    float* pad = (float*)hbuf;
    const int c = wn * 4 + g;                 // 16 partials per row
    #pragma unroll
    for (int rf = 0; rf < 4; ++rf) {
      const int r = wr0 + rf * 16 + ml;
      float p = 0.f;
      #pragma unroll
      for (int nf = 0; nf < 4; ++nf) {
        #pragma unroll
        for (int q = 0; q < 4; ++q)
          p += fmaxf(acc[nf][rf][q], 0.f) * wfv[nf][q];
      }
      pad[r * 17 + c] = p;
    }
    bar_lgkm();

    // reduce: 4 threads per row sum 4 partials each -> e = exp(logit)
    {
      const int row  = tid >> 2;   // 0..127
      const int part = tid & 3;
      const float* pr = pad + row * 17 + part * 4;
      float s = pr[0] + pr[1] + pr[2] + pr[3];
      s += __shfl_xor(s, 1);
      s += __shfl_xor(s, 2);
      if (part == 0)
        out[OUT_P + (size_t)(r0 + row)] = __expf(s + bf_s);
    }
  }
}

// ---- K2: fused segment softmax-denominator + divide + g_emb copy ----
__global__ __launch_bounds__(256) void k_soft(
    const float* __restrict__ g_emb, const int* __restrict__ bidx,
    float* __restrict__ out)
{
  const int b   = blockIdx.x;
  const int tid = threadIdx.x;
  __shared__ float ws[4];
  __shared__ float sden;

  int lo = 0, hi = N_CAND;
  while (lo < hi) { int m = (lo + hi) >> 1; if (bidx[m] < b) lo = m + 1; else hi = m; }
  int lo2 = lo, hi2 = N_CAND;
  while (lo2 < hi2) { int m = (lo2 + hi2) >> 1; if (bidx[m] < b + 1) lo2 = m + 1; else hi2 = m; }

  float s = 0.f;
  for (int i = lo + tid; i < lo2; i += 256) s += out[OUT_P + (size_t)i];
  #pragma unroll
  for (int off = 32; off > 0; off >>= 1) s += __shfl_down(s, off);
  if ((tid & 63) == 0) ws[tid >> 6] = s;
  __syncthreads();
  if (tid == 0) sden = ws[0] + ws[1] + ws[2] + ws[3];
  __syncthreads();
  const float d = sden;
  for (int i = lo + tid; i < lo2; i += 256)
    out[OUT_P + (size_t)i] = out[OUT_P + (size_t)i] / d;

  if (tid < 32) {
    f32x4 v = *(const f32x4*)(g_emb + (size_t)b * EMB + tid * 4);
    *(f32x4*)(out + (size_t)b * EMB + tid * 4) = v;
  }
}

extern "C" void kernel_launch(void* const* d_in, const int* in_sizes, int n_in,
                              void* d_out, int out_size, void* d_ws, size_t ws_size,
                              hipStream_t stream)
{
  const float* g_emb = (const float*)d_in[0];
  const float* cand  = (const float*)d_in[1];
  const float* W1    = (const float*)d_in[2];
  const float* b1    = (const float*)d_in[3];
  const float* W2    = (const float*)d_in[4];
  const float* b2    = (const float*)d_in[5];
  const float* W3    = (const float*)d_in[6];
  const float* b3    = (const float*)d_in[7];
  const float* Wf    = (const float*)d_in[8];
  const float* bfp   = (const float*)d_in[9];
  const int*   bidx  = (const int*)d_in[10];
  float* out = (float*)d_out;

  u16* wt = (u16*)d_ws;    // 3 * 128 KB packed bf16 weights

  k_prep <<<768, 256, 0, stream>>>(W1, W2, W3, wt);
  k_main <<<NBLK, 512, 0, stream>>>(g_emb, cand, bidx, b1, b2, b3, Wf, bfp, wt, out);
  k_soft <<<BGR, 256, 0, stream>>>(g_emb, bidx, out);
}

// Round 14
// 330.452 us; speedup vs baseline: 2.5972x; 1.1922x over previous
//
#include <hip/hip_runtime.h>
#include <hip/hip_bf16.h>
#include <math.h>

#define N_CAND 524288
#define RB     128
#define NBLK   (N_CAND / RB)     // 4096
#define EMB    128
#define HID    256
#define BGR    2048

#define OUT_XS  262144                      // offset of X_states in out (floats)
#define OUT_P   (262144 + 134217728)        // offset of probs in out (floats)

typedef __attribute__((ext_vector_type(4)))  float f32x4;
typedef __attribute__((ext_vector_type(16))) float f32x16;
typedef __attribute__((ext_vector_type(8)))  short bf16x8;
typedef __attribute__((ext_vector_type(4)))  short bf16x4;
typedef unsigned short u16;

// Native convert (RNE): pairs compile to v_cvt_pk_bf16_f32.
__device__ __forceinline__ u16 f2bf(float f) {
  __hip_bfloat16 h = __float2bfloat16(f);
  return *reinterpret_cast<u16*>(&h);
}

// Raw barrier: waits LDS ops only (lgkmcnt), does NOT drain vmcnt.
// Global stores (X_states) keep flowing under later phases.
__device__ __forceinline__ void bar_lgkm() {
  __builtin_amdgcn_sched_barrier(0);
  asm volatile("s_waitcnt lgkmcnt(0)" ::: "memory");
  __builtin_amdgcn_sched_barrier(0);
  __builtin_amdgcn_s_barrier();
  __builtin_amdgcn_sched_barrier(0);
}
__device__ __forceinline__ void bar_only() {
  __builtin_amdgcn_sched_barrier(0);
  __builtin_amdgcn_s_barrier();
  __builtin_amdgcn_sched_barrier(0);
}

// ---- K0: W1/W2/W3 (f32, [k][n]) -> 32x32x16-fragment-packed bf16 ----
// A-frag layout (32x32x16): row n = lane&31, k = (lane>>5)*8 + j.
// Element (m, n, k): nt=n>>5, ks=k>>4, klo=k&15, lane=(n&31)+32*(klo>>3),
// j=klo&7.  dst u16 = ((m*8+nt)*16+ks)*512 + lane*8 + j.
// A wave's A-fragment load (nt,ks) is 64 lanes x 16B = 1 KB contiguous.
__global__ void k_prep(const float* __restrict__ W1, const float* __restrict__ W2,
                       const float* __restrict__ W3, u16* __restrict__ wt) {
  const int b = blockIdx.x;
  const int m = b >> 8;          // which matrix
  const int n = b & 255;         // output unit
  const int k = threadIdx.x;     // input unit
  const float* W = (m == 0) ? W1 : ((m == 1) ? W2 : W3);
  const int nt = n >> 5, ks = k >> 4, klo = k & 15;
  const int lane = (n & 31) + ((klo >> 3) << 5);
  const int j = klo & 7;
  wt[(((m * 8 + nt) * 16 + ks) << 9) + lane * 8 + j] = f2bf(W[k * 256 + n]);
}

// K-loop (32x32x16): wave owns 32n x 128r, acc = 4 x f32x16 = 64 AGPR.
// Per ks: 1 packed A-load (1KB, L2) + 4 ds_read_b128 + 4 MFMA.
// acc initialized from bias fragment (free bias via MFMA C-in).
__device__ __forceinline__ void mfma_k32(const char* wl, const char* hbc,
                                         int kofs, int swzB, const float* bs,
                                         int wn0, int l5, f32x16 (&acc)[4])
{
  #pragma unroll
  for (int q = 0; q < 4; ++q) {
    const f32x4 bq = *(const f32x4*)(bs + wn0 + 8 * q + 4 * l5);
    #pragma unroll
    for (int e = 0; e < 4; ++e) {
      #pragma unroll
      for (int rt = 0; rt < 4; ++rt)
        acc[rt][4 * q + e] = bq[e];
    }
  }

  __builtin_amdgcn_s_setprio(1);
  #pragma unroll
  for (int ks = 0; ks < 16; ++ks) {
    const bf16x8 a = *(const bf16x8*)(wl + ks * 1024);     // 1KB coalesced (L2)
    bf16x8 b[4];
    #pragma unroll
    for (int rt = 0; rt < 4; ++rt)
      b[rt] = *(const bf16x8*)(hbc + rt * 16384 + ((ks * 32 + kofs) ^ swzB));
    #pragma unroll
    for (int rt = 0; rt < 4; ++rt)
      acc[rt] = __builtin_amdgcn_mfma_f32_32x32x16_bf16(a, b[rt], acc[rt], 0, 0, 0);
  }
  __builtin_amdgcn_s_setprio(0);
}

// Epilogue (layers 1,2): relu, ->bf16, in-place swizzled write (bias pre-added).
// D layout: col r = lane&31, n = (reg&3) + 8*(reg>>2) + 4*(lane>>5).
__device__ __forceinline__ void epi32(char* hb, int wn0, int cl, int l5,
                                      const f32x16 (&acc)[4])
{
  const int swz = (cl & 15) << 4;
  #pragma unroll
  for (int rt = 0; rt < 4; ++rt) {
    const int r = rt * 32 + cl;
    #pragma unroll
    for (int q = 0; q < 4; ++q) {
      const int n0q = wn0 + 8 * q + 4 * l5;
      bf16x4 hv;
      #pragma unroll
      for (int e = 0; e < 4; ++e)
        hv[e] = (short)f2bf(fmaxf(acc[rt][4 * q + e], 0.f));
      *(bf16x4*)(hb + r * 512 + ((n0q * 2) ^ swz)) = hv;
    }
  }
}

// ---- K1: fused X-concat/X_states write + 3-layer MLP + fused head ----
// Champion (r10) structure, MFMA shape 32x32x16: 8 waves, RB=128,
// wave w owns n in [w*32, w*32+32) for ALL 128 rows (weights once/block).
// Raw lgkm-only barriers: X_states stores never drained at a barrier.
__global__ __launch_bounds__(512, 4) void k_main(
    const float* __restrict__ g_emb, const float* __restrict__ cand,
    const int* __restrict__ bidx,
    const float* __restrict__ b1, const float* __restrict__ b2,
    const float* __restrict__ b3, const float* __restrict__ Wf,
    const float* __restrict__ bfp, const u16* __restrict__ wt,
    float* __restrict__ out)
{
  __shared__ __align__(16) u16 hbuf[RB * HID];   // 64 KB, chunk-XOR swizzled
  __shared__ float bias_s[3 * HID];
  __shared__ float bf_s;

  const int tid = threadIdx.x;
  const int r0  = blockIdx.x * RB;

  if (tid < HID) {
    bias_s[tid]           = b1[tid];
    bias_s[HID + tid]     = b2[tid];
    bias_s[2 * HID + tid] = b3[tid];
    if (tid == 0) bf_s = bfp[0];
  }

  // ---- stage X (concat) into LDS bf16 swizzled; write X_states f32 ----
  {
    const int kc   = tid & 31;    // 16B chunk (8 elems) within the 256-col row
    const int row0 = tid >> 5;    // 0..15
    char* l0 = (char*)hbuf;
    int bpre[8];
    #pragma unroll
    for (int i = 0; i < 8; ++i)
      bpre[i] = bidx[r0 + row0 + i * 16];   // break dependent-load chain
    #pragma unroll
    for (int i = 0; i < 8; ++i) {
      const int row = row0 + i * 16;        // 0..127
      const int r   = r0 + row;
      const float* src = (kc < 16)
          ? g_emb + (size_t)bpre[i] * EMB + kc * 8
          : cand  + (size_t)r * EMB + (kc - 16) * 8;
      f32x4 v0 = *(const f32x4*)(src);
      f32x4 v1 = *(const f32x4*)(src + 4);
      float* dst = out + OUT_XS + (size_t)r * (2 * EMB) + kc * 8;
      *(f32x4*)dst       = v0;   // async: never waited before a barrier
      *(f32x4*)(dst + 4) = v1;
      bf16x8 hv;
      hv[0] = (short)f2bf(v0.x); hv[1] = (short)f2bf(v0.y);
      hv[2] = (short)f2bf(v0.z); hv[3] = (short)f2bf(v0.w);
      hv[4] = (short)f2bf(v1.x); hv[5] = (short)f2bf(v1.y);
      hv[6] = (short)f2bf(v1.z); hv[7] = (short)f2bf(v1.w);
      *(bf16x8*)(l0 + row * 512 + ((kc * 16) ^ ((row & 15) << 4))) = hv;
    }
  }
  bar_lgkm();

  const int lane = tid & 63;
  const int w    = tid >> 6;          // 0..7
  const int cl   = lane & 31;         // data-row within 32-tile (B col)
  const int l5   = lane >> 5;         // 0/1: k-half
  const int wn0  = w * 32;            // n-stripe

  const int swzB = (cl & 15) << 4;
  const int kofs = l5 * 16;
  char* const hb  = (char*)hbuf;
  const char* const hbc = hb + (size_t)cl * 512;  // + rt*16384 per row-tile

  f32x16 acc[4];

  // ---- layers 1,2 ----
  mfma_k32((const char*)wt + (size_t)((0 * 8 + w) * 16) * 1024 + lane * 16,
           hbc, kofs, swzB, bias_s, wn0, l5, acc);
  bar_only();
  epi32(hb, wn0, cl, l5, acc);
  bar_lgkm();

  mfma_k32((const char*)wt + (size_t)((1 * 8 + w) * 16) * 1024 + lane * 16,
           hbc, kofs, swzB, bias_s + HID, wn0, l5, acc);
  bar_only();
  epi32(hb, wn0, cl, l5, acc);
  bar_lgkm();

  // ---- layer 3 + head, fused: h3 stays in registers ----
  mfma_k32((const char*)wt + (size_t)((2 * 8 + w) * 16) * 1024 + lane * 16,
           hbc, kofs, swzB, bias_s + 2 * HID, wn0, l5, acc);
  bar_only();   // all h2 reads done -> hbuf reusable as reduction pad
  {
    f32x4 wfq[4];
    #pragma unroll
    for (int q = 0; q < 4; ++q)
      wfq[q] = *(const f32x4*)(Wf + wn0 + 8 * q + 4 * l5);

    // pad[128][17] f32: stride-17 -> writer lanes spread across banks
    float* pad = (float*)hbuf;
    const int c = w * 2 + l5;                 // 16 partials per row
    #pragma unroll
    for (int rt = 0; rt < 4; ++rt) {
      const int r = rt * 32 + cl;
      float p = 0.f;
      #pragma unroll
      for (int q = 0; q < 4; ++q) {
        #pragma unroll
        for (int e = 0; e < 4; ++e)
          p += fmaxf(acc[rt][4 * q + e], 0.f) * wfq[q][e];
      }
      pad[r * 17 + c] = p;
    }
    bar_lgkm();

    // reduce: 4 threads per row sum 4 partials each -> e = exp(logit)
    {
      const int row  = tid >> 2;   // 0..127
      const int part = tid & 3;
      const float* pr = pad + row * 17 + part * 4;
      float s = pr[0] + pr[1] + pr[2] + pr[3];
      s += __shfl_xor(s, 1);
      s += __shfl_xor(s, 2);
      if (part == 0)
        out[OUT_P + (size_t)(r0 + row)] = __expf(s + bf_s);
    }
  }
}

// ---- K2: fused segment softmax-denominator + divide + g_emb copy ----
__global__ __launch_bounds__(256) void k_soft(
    const float* __restrict__ g_emb, const int* __restrict__ bidx,
    float* __restrict__ out)
{
  const int b   = blockIdx.x;
  const int tid = threadIdx.x;
  __shared__ float ws[4];
  __shared__ float sden;

  int lo = 0, hi = N_CAND;
  while (lo < hi) { int m = (lo + hi) >> 1; if (bidx[m] < b) lo = m + 1; else hi = m; }
  int lo2 = lo, hi2 = N_CAND;
  while (lo2 < hi2) { int m = (lo2 + hi2) >> 1; if (bidx[m] < b + 1) lo2 = m + 1; else hi2 = m; }

  float s = 0.f;
  for (int i = lo + tid; i < lo2; i += 256) s += out[OUT_P + (size_t)i];
  #pragma unroll
  for (int off = 32; off > 0; off >>= 1) s += __shfl_down(s, off);
  if ((tid & 63) == 0) ws[tid >> 6] = s;
  __syncthreads();
  if (tid == 0) sden = ws[0] + ws[1] + ws[2] + ws[3];
  __syncthreads();
  const float d = sden;
  for (int i = lo + tid; i < lo2; i += 256)
    out[OUT_P + (size_t)i] = out[OUT_P + (size_t)i] / d;

  if (tid < 32) {
    f32x4 v = *(const f32x4*)(g_emb + (size_t)b * EMB + tid * 4);
    *(f32x4*)(out + (size_t)b * EMB + tid * 4) = v;
  }
}

extern "C" void kernel_launch(void* const* d_in, const int* in_sizes, int n_in,
                              void* d_out, int out_size, void* d_ws, size_t ws_size,
                              hipStream_t stream)
{
  const float* g_emb = (const float*)d_in[0];
  const float* cand  = (const float*)d_in[1];
  const float* W1    = (const float*)d_in[2];
  const float* b1    = (const float*)d_in[3];
  const float* W2    = (const float*)d_in[4];
  const float* b2    = (const float*)d_in[5];
  const float* W3    = (const float*)d_in[6];
  const float* b3    = (const float*)d_in[7];
  const float* Wf    = (const float*)d_in[8];
  const float* bfp   = (const float*)d_in[9];
  const int*   bidx  = (const int*)d_in[10];
  float* out = (float*)d_out;

  u16* wt = (u16*)d_ws;    // 3 * 128 KB packed bf16 weights

  k_prep <<<768, 256, 0, stream>>>(W1, W2, W3, wt);
  k_main <<<NBLK, 512, 0, stream>>>(g_emb, cand, bidx, b1, b2, b3, Wf, bfp, wt, out);
  k_soft <<<BGR, 256, 0, stream>>>(g_emb, bidx, out);
}

// Round 15
// 323.137 us; speedup vs baseline: 2.6560x; 1.0226x over previous
//
#include <hip/hip_runtime.h>
#include <hip/hip_bf16.h>
#include <math.h>

#define N_CAND 524288
#define RB     128
#define NBLK   (N_CAND / RB)     // 4096
#define EMB    128
#define HID    256
#define BGR    2048

#define OUT_XS  262144                      // offset of X_states in out (floats)
#define OUT_P   (262144 + 134217728)        // offset of probs in out (floats)

typedef __attribute__((ext_vector_type(4))) float f32x4;
typedef __attribute__((ext_vector_type(8))) short bf16x8;
typedef __attribute__((ext_vector_type(4))) short bf16x4;
typedef unsigned short u16;

// Native convert (RNE): pairs compile to v_cvt_pk_bf16_f32.
__device__ __forceinline__ u16 f2bf(float f) {
  __hip_bfloat16 h = __float2bfloat16(f);
  return *reinterpret_cast<u16*>(&h);
}

// Raw barrier: waits LDS ops only (lgkmcnt), does NOT drain vmcnt.
// Global stores (X_states) keep flowing under later phases.
__device__ __forceinline__ void bar_lgkm() {
  __builtin_amdgcn_sched_barrier(0);
  asm volatile("s_waitcnt lgkmcnt(0)" ::: "memory");
  __builtin_amdgcn_sched_barrier(0);
  __builtin_amdgcn_s_barrier();
  __builtin_amdgcn_sched_barrier(0);
}
__device__ __forceinline__ void bar_only() {
  __builtin_amdgcn_sched_barrier(0);
  __builtin_amdgcn_s_barrier();
  __builtin_amdgcn_sched_barrier(0);
}

// ---- K0: W1/W2/W3 (f32, [k][n]) -> MFMA-fragment-packed bf16 (16x16x32) ----
// dst u16 index = ((L*16+nt)*8+ks)*512 + lane*8 + j  (lane = g*16+ml).
// A wave's A-fragment load (nt,ks) is 64 lanes x 16B = 1 KB contiguous.
__global__ void k_prep(const float* __restrict__ W1, const float* __restrict__ W2,
                       const float* __restrict__ W3, u16* __restrict__ wt) {
  const int b = blockIdx.x;
  const int m = b >> 8;          // which matrix
  const int n = b & 255;         // output unit
  const int k = threadIdx.x;     // input unit
  const float* W = (m == 0) ? W1 : ((m == 1) ? W2 : W3);
  const int nt = n >> 4, ml = n & 15;
  const int ks = k >> 5, g = (k >> 3) & 3, j = k & 7;
  const int lane = g * 16 + ml;
  wt[(((m * 16 + nt) * 8 + ks) << 9) + lane * 8 + j] = f2bf(W[k * 256 + n]);
}

// K-loop (champion geometry): wave owns 32n x 128r, acc[2][8] = 64 AGPR.
// acc initialized from the bias fragment (free bias via MFMA C-in).
__device__ __forceinline__ void mfma_k(const char* wl, const char* hbr, int bofs,
                                       const float* bs, int wn0, int g,
                                       f32x4 (&acc)[2][8])
{
  #pragma unroll
  for (int nf = 0; nf < 2; ++nf) {
    const f32x4 bb = *(const f32x4*)(bs + wn0 + nf * 16 + g * 4);
    #pragma unroll
    for (int rf = 0; rf < 8; ++rf)
      acc[nf][rf] = bb;
  }

  __builtin_amdgcn_s_setprio(1);
  #pragma unroll
  for (int ks = 0; ks < 8; ++ks) {
    bf16x8 a[2];
    #pragma unroll
    for (int nf = 0; nf < 2; ++nf)
      a[nf] = *(const bf16x8*)(wl + (nf * 8 + ks) * 1024);       // 1KB coalesced
    #pragma unroll
    for (int rh = 0; rh < 2; ++rh) {
      bf16x8 bq[4];
      #pragma unroll
      for (int rj = 0; rj < 4; ++rj)
        bq[rj] = *(const bf16x8*)(hbr + (rh * 4 + rj) * 8192 + ((ks * 64) ^ bofs));
      #pragma unroll
      for (int nf = 0; nf < 2; ++nf)
        #pragma unroll
        for (int rj = 0; rj < 4; ++rj)
          acc[nf][rh * 4 + rj] = __builtin_amdgcn_mfma_f32_16x16x32_bf16(
              a[nf], bq[rj], acc[nf][rh * 4 + rj], 0, 0, 0);
    }
  }
  __builtin_amdgcn_s_setprio(0);
}

// Epilogue (layers 1,2): relu, ->bf16, in-place swizzled write (bias pre-added).
__device__ __forceinline__ void epi(char* hb, int wn0, int g, int ml, int swz,
                                    const f32x4 (&acc)[2][8])
{
  #pragma unroll
  for (int nf = 0; nf < 2; ++nf) {
    const int n0 = wn0 + nf * 16 + g * 4;
    #pragma unroll
    for (int rf = 0; rf < 8; ++rf) {
      const int r = rf * 16 + ml;
      bf16x4 hv;
      #pragma unroll
      for (int q = 0; q < 4; ++q)
        hv[q] = (short)f2bf(fmaxf(acc[nf][rf][q], 0.f));
      *(bf16x4*)(hb + r * 512 + ((n0 * 2) ^ swz)) = hv;
    }
  }
}

// ---- K1: fused X-concat/X_states write + 3-layer MLP + fused head ----
// Exact r10 champion structure (8 waves, RB=128, weights once/block,
// 2 blocks/CU, lgkm-only barriers); single delta: bias via acc C-init.
__global__ __launch_bounds__(512, 4) void k_main(
    const float* __restrict__ g_emb, const float* __restrict__ cand,
    const int* __restrict__ bidx,
    const float* __restrict__ b1, const float* __restrict__ b2,
    const float* __restrict__ b3, const float* __restrict__ Wf,
    const float* __restrict__ bfp, const u16* __restrict__ wt,
    float* __restrict__ out)
{
  __shared__ __align__(16) u16 hbuf[RB * HID];   // 64 KB, chunk-XOR swizzled
  __shared__ float bias_s[3 * HID];
  __shared__ float bf_s;

  const int tid = threadIdx.x;
  const int r0  = blockIdx.x * RB;

  if (tid < HID) {
    bias_s[tid]           = b1[tid];
    bias_s[HID + tid]     = b2[tid];
    bias_s[2 * HID + tid] = b3[tid];
    if (tid == 0) bf_s = bfp[0];
  }

  // ---- stage X (concat) into LDS bf16 swizzled; write X_states f32 ----
  {
    const int kc   = tid & 31;    // 16B chunk (8 elems) within the 256-col row
    const int row0 = tid >> 5;    // 0..15
    char* l0 = (char*)hbuf;
    int bpre[8];
    #pragma unroll
    for (int i = 0; i < 8; ++i)
      bpre[i] = bidx[r0 + row0 + i * 16];   // break dependent-load chain
    #pragma unroll
    for (int i = 0; i < 8; ++i) {
      const int row = row0 + i * 16;        // 0..127
      const int r   = r0 + row;
      const float* src = (kc < 16)
          ? g_emb + (size_t)bpre[i] * EMB + kc * 8
          : cand  + (size_t)r * EMB + (kc - 16) * 8;
      f32x4 v0 = *(const f32x4*)(src);
      f32x4 v1 = *(const f32x4*)(src + 4);
      float* dst = out + OUT_XS + (size_t)r * (2 * EMB) + kc * 8;
      *(f32x4*)dst       = v0;   // async: never waited before a barrier
      *(f32x4*)(dst + 4) = v1;
      bf16x8 hv;
      hv[0] = (short)f2bf(v0.x); hv[1] = (short)f2bf(v0.y);
      hv[2] = (short)f2bf(v0.z); hv[3] = (short)f2bf(v0.w);
      hv[4] = (short)f2bf(v1.x); hv[5] = (short)f2bf(v1.y);
      hv[6] = (short)f2bf(v1.z); hv[7] = (short)f2bf(v1.w);
      *(bf16x8*)(l0 + row * 512 + ((kc * 16) ^ ((row & 15) << 4))) = hv;
    }
  }
  bar_lgkm();

  const int lane = tid & 63;
  const int w    = tid >> 6;          // 0..7
  const int ml   = lane & 15;
  const int g    = lane >> 4;         // 0..3
  const int wn0  = w * 32;            // n-offset: 2 tiles of 16 per wave

  const int swz  = ml << 4;                 // row-swizzle ((rf*16+ml)&15 == ml)
  const int bofs = (g * 16) ^ swz;          // k-chunk xor per lane
  char* const hb  = (char*)hbuf;
  const char* const hbr = hb + (size_t)ml * 512;  // B-read base

  f32x4 acc[2][8];

  // ---- layers 1,2 ----
  mfma_k((const char*)wt + (size_t)((0 * 16 + w * 2) * 8) * 1024 + lane * 16,
         hbr, bofs, bias_s, wn0, g, acc);
  bar_only();
  epi(hb, wn0, g, ml, swz, acc);
  bar_lgkm();

  mfma_k((const char*)wt + (size_t)((1 * 16 + w * 2) * 8) * 1024 + lane * 16,
         hbr, bofs, bias_s + HID, wn0, g, acc);
  bar_only();
  epi(hb, wn0, g, ml, swz, acc);
  bar_lgkm();

  // ---- layer 3 + head, fused: h3 stays in registers ----
  mfma_k((const char*)wt + (size_t)((2 * 16 + w * 2) * 8) * 1024 + lane * 16,
         hbr, bofs, bias_s + 2 * HID, wn0, g, acc);
  bar_only();   // all h2 reads done -> hbuf reusable as reduction pad
  {
    const f32x4 wf0 = *(const f32x4*)(Wf + wn0 + g * 4);
    const f32x4 wf1 = *(const f32x4*)(Wf + wn0 + 16 + g * 4);

    float* pad = (float*)hbuf;   // [128][32] f32 partials, slot-swizzled
    #pragma unroll
    for (int rf = 0; rf < 8; ++rf) {
      const int r = rf * 16 + ml;
      float p = 0.f;
      #pragma unroll
      for (int q = 0; q < 4; ++q) {
        p += fmaxf(acc[0][rf][q], 0.f) * wf0[q];
        p += fmaxf(acc[1][rf][q], 0.f) * wf1[q];
      }
      const int slot = (w * 4 + g) ^ ((r & 7) << 2);   // conflict-free banks
      pad[r * 32 + slot] = p;
    }
    bar_lgkm();

    // reduce: 4 threads per row sum 32 partials -> e = exp(logit)
    {
      const int row  = tid >> 2;   // 0..127
      const int part = tid & 3;
      const int sx   = (row & 7) << 2;
      f32x4 v0 = *(const f32x4*)(pad + row * 32 + ((part * 8) ^ sx));
      f32x4 v1 = *(const f32x4*)(pad + row * 32 + ((part * 8 + 4) ^ sx));
      float s = v0[0] + v0[1] + v0[2] + v0[3] + v1[0] + v1[1] + v1[2] + v1[3];
      s += __shfl_xor(s, 1);
      s += __shfl_xor(s, 2);
      if (part == 0)
        out[OUT_P + (size_t)(r0 + row)] = __expf(s + bf_s);
    }
  }
}

// ---- K2: fused segment softmax-denominator + divide + g_emb copy ----
__global__ __launch_bounds__(256) void k_soft(
    const float* __restrict__ g_emb, const int* __restrict__ bidx,
    float* __restrict__ out)
{
  const int b   = blockIdx.x;
  const int tid = threadIdx.x;
  __shared__ float ws[4];
  __shared__ float sden;

  int lo = 0, hi = N_CAND;
  while (lo < hi) { int m = (lo + hi) >> 1; if (bidx[m] < b) lo = m + 1; else hi = m; }
  int lo2 = lo, hi2 = N_CAND;
  while (lo2 < hi2) { int m = (lo2 + hi2) >> 1; if (bidx[m] < b + 1) lo2 = m + 1; else hi2 = m; }

  float s = 0.f;
  for (int i = lo + tid; i < lo2; i += 256) s += out[OUT_P + (size_t)i];
  #pragma unroll
  for (int off = 32; off > 0; off >>= 1) s += __shfl_down(s, off);
  if ((tid & 63) == 0) ws[tid >> 6] = s;
  __syncthreads();
  if (tid == 0) sden = ws[0] + ws[1] + ws[2] + ws[3];
  __syncthreads();
  const float d = sden;
  for (int i = lo + tid; i < lo2; i += 256)
    out[OUT_P + (size_t)i] = out[OUT_P + (size_t)i] / d;

  if (tid < 32) {
    f32x4 v = *(const f32x4*)(g_emb + (size_t)b * EMB + tid * 4);
    *(f32x4*)(out + (size_t)b * EMB + tid * 4) = v;
  }
}

extern "C" void kernel_launch(void* const* d_in, const int* in_sizes, int n_in,
                              void* d_out, int out_size, void* d_ws, size_t ws_size,
                              hipStream_t stream)
{
  const float* g_emb = (const float*)d_in[0];
  const float* cand  = (const float*)d_in[1];
  const float* W1    = (const float*)d_in[2];
  const float* b1    = (const float*)d_in[3];
  const float* W2    = (const float*)d_in[4];
  const float* b2    = (const float*)d_in[5];
  const float* W3    = (const float*)d_in[6];
  const float* b3    = (const float*)d_in[7];
  const float* Wf    = (const float*)d_in[8];
  const float* bfp   = (const float*)d_in[9];
  const int*   bidx  = (const int*)d_in[10];
  float* out = (float*)d_out;

  u16* wt = (u16*)d_ws;    // 3 * 128 KB packed bf16 weights

  k_prep <<<768, 256, 0, stream>>>(W1, W2, W3, wt);
  k_main <<<NBLK, 512, 0, stream>>>(g_emb, cand, bidx, b1, b2, b3, Wf, bfp, wt, out);
  k_soft <<<BGR, 256, 0, stream>>>(g_emb, bidx, out);
}

// Round 16
// 268.146 us; speedup vs baseline: 3.2006x; 1.2051x over previous
//
#include <hip/hip_runtime.h>
#include <hip/hip_bf16.h>
#include <math.h>

#define N_CAND 524288
#define RB     128
#define NBLK   (N_CAND / RB)     // 4096
#define EMB    128
#define HID    256
#define BGR    2048

#define OUT_XS  262144                      // offset of X_states in out (floats)
#define OUT_P   (262144 + 134217728)        // offset of probs in out (floats)

typedef __attribute__((ext_vector_type(4))) float f32x4;
typedef __attribute__((ext_vector_type(8))) short bf16x8;
typedef __attribute__((ext_vector_type(4))) short bf16x4;
typedef unsigned short u16;

// Native convert (RNE): pairs compile to v_cvt_pk_bf16_f32.
__device__ __forceinline__ u16 f2bf(float f) {
  __hip_bfloat16 h = __float2bfloat16(f);
  return *reinterpret_cast<u16*>(&h);
}

// Raw barrier: waits LDS ops only (lgkmcnt), does NOT drain vmcnt.
// Global stores (X_states) keep flowing under later phases.
__device__ __forceinline__ void bar_lgkm() {
  __builtin_amdgcn_sched_barrier(0);
  asm volatile("s_waitcnt lgkmcnt(0)" ::: "memory");
  __builtin_amdgcn_sched_barrier(0);
  __builtin_amdgcn_s_barrier();
  __builtin_amdgcn_sched_barrier(0);
}
__device__ __forceinline__ void bar_only() {
  __builtin_amdgcn_sched_barrier(0);
  __builtin_amdgcn_s_barrier();
  __builtin_amdgcn_sched_barrier(0);
}

// ---- K0: W1/W2/W3 (f32, [k][n]) -> MFMA-fragment-packed bf16 ----
// dst u16 index = ((L*16+nt)*8+ks)*512 + lane*8 + j  (lane = g*16+ml).
// A wave's A-fragment load (nt,ks) is then 64 lanes x 16B = 1 KB contiguous.
__global__ void k_prep(const float* __restrict__ W1, const float* __restrict__ W2,
                       const float* __restrict__ W3, u16* __restrict__ wt) {
  const int b = blockIdx.x;
  const int m = b >> 8;          // which matrix
  const int n = b & 255;         // output unit
  const int k = threadIdx.x;     // input unit
  const float* W = (m == 0) ? W1 : ((m == 1) ? W2 : W3);
  const int nt = n >> 4, ml = n & 15;
  const int ks = k >> 5, g = (k >> 3) & 3, j = k & 7;
  const int lane = g * 16 + ml;
  wt[(((m * 16 + nt) * 8 + ks) << 9) + lane * 8 + j] = f2bf(W[k * 256 + n]);
}

// One MLP layer on buf (in place): champion inner geometry.
// Wave w owns n in [w*32, w*32+32) for all 128 rows.
__device__ __forceinline__ void mlp_layer(
    int Lidx, u16* buf, const u16* __restrict__ wt, const float* bias_s,
    int w, int lane, int ml, int g, int wn0, int swz, int bofs)
{
  const char* wl = (const char*)wt +
      ((size_t)(Lidx * 16 + w * 2) * 8) * 1024 + lane * 16;
  const float* bs = bias_s + Lidx * HID;
  char* const hb  = (char*)buf;
  char* const hbr = hb + (size_t)ml * 512;

  f32x4 acc[2][8];   // [nf][rf] = 64 AGPR
  #pragma unroll
  for (int nf = 0; nf < 2; ++nf)
    #pragma unroll
    for (int rf = 0; rf < 8; ++rf)
      acc[nf][rf] = (f32x4){0.f, 0.f, 0.f, 0.f};

  __builtin_amdgcn_s_setprio(1);
  #pragma unroll
  for (int ks = 0; ks < 8; ++ks) {
    bf16x8 a[2];
    #pragma unroll
    for (int nf = 0; nf < 2; ++nf)
      a[nf] = *(const bf16x8*)(wl + (nf * 8 + ks) * 1024);       // 1KB coalesced
    #pragma unroll
    for (int rh = 0; rh < 2; ++rh) {
      bf16x8 bq[4];
      #pragma unroll
      for (int rj = 0; rj < 4; ++rj)
        bq[rj] = *(const bf16x8*)(hbr + (rh * 4 + rj) * 8192 + ((ks * 64) ^ bofs));
      #pragma unroll
      for (int nf = 0; nf < 2; ++nf)
        #pragma unroll
        for (int rj = 0; rj < 4; ++rj)
          acc[nf][rh * 4 + rj] = __builtin_amdgcn_mfma_f32_16x16x32_bf16(
              a[nf], bq[rj], acc[nf][rh * 4 + rj], 0, 0, 0);
    }
  }
  __builtin_amdgcn_s_setprio(0);
  bar_only();   // all reads of buf done -> safe to overwrite in place

  #pragma unroll
  for (int nf = 0; nf < 2; ++nf) {
    const int n0 = wn0 + nf * 16 + g * 4;
    const f32x4 bb = *(const f32x4*)(bs + n0);
    #pragma unroll
    for (int rf = 0; rf < 8; ++rf) {
      const int r = rf * 16 + ml;
      bf16x4 hv;
      #pragma unroll
      for (int q = 0; q < 4; ++q) {
        float x = acc[nf][rf][q] + bb[q];
        x = fmaxf(x, 0.f);
        hv[q] = (short)f2bf(x);
      }
      *(bf16x4*)(hb + r * 512 + ((n0 * 2) ^ swz)) = hv;
    }
  }
  bar_lgkm();
}

// ---- K1: fused X-concat/X_states write + 3-layer MLP + fused head ----
// Exact r10 champion; single delta: X_states stores are NON-TEMPORAL
// (bypass L2/L3 allocation) so the 527 MB write stream stops evicting
// cand (L3) and the packed weights (L2).
__global__ __launch_bounds__(512, 4) void k_main(
    const float* __restrict__ g_emb, const float* __restrict__ cand,
    const int* __restrict__ bidx,
    const float* __restrict__ b1, const float* __restrict__ b2,
    const float* __restrict__ b3, const float* __restrict__ Wf,
    const float* __restrict__ bfp, const u16* __restrict__ wt,
    float* __restrict__ out)
{
  __shared__ __align__(16) u16 hbuf[RB * HID];   // 64 KB, chunk-XOR swizzled
  __shared__ float bias_s[3 * HID];
  __shared__ float bf_s;

  const int tid = threadIdx.x;
  const int r0  = blockIdx.x * RB;

  if (tid < HID) {
    bias_s[tid]           = b1[tid];
    bias_s[HID + tid]     = b2[tid];
    bias_s[2 * HID + tid] = b3[tid];
    if (tid == 0) bf_s = bfp[0];
  }

  // ---- stage X (concat) into LDS bf16 swizzled; write X_states f32 (nt) ----
  {
    const int kc   = tid & 31;    // 16B chunk (8 elems) within the 256-col row
    const int row0 = tid >> 5;    // 0..15
    char* l0 = (char*)hbuf;
    int bpre[8];
    #pragma unroll
    for (int i = 0; i < 8; ++i)
      bpre[i] = bidx[r0 + row0 + i * 16];   // break dependent-load chain
    #pragma unroll
    for (int i = 0; i < 8; ++i) {
      const int row = row0 + i * 16;        // 0..127
      const int r   = r0 + row;
      const float* src = (kc < 16)
          ? g_emb + (size_t)bpre[i] * EMB + kc * 8
          : cand  + (size_t)r * EMB + (kc - 16) * 8;
      f32x4 v0 = *(const f32x4*)(src);
      f32x4 v1 = *(const f32x4*)(src + 4);
      float* dst = out + OUT_XS + (size_t)r * (2 * EMB) + kc * 8;
      __builtin_nontemporal_store(v0, (f32x4*)dst);        // nt: no cache alloc
      __builtin_nontemporal_store(v1, (f32x4*)(dst + 4));  // fire-and-forget
      bf16x8 hv;
      hv[0] = (short)f2bf(v0.x); hv[1] = (short)f2bf(v0.y);
      hv[2] = (short)f2bf(v0.z); hv[3] = (short)f2bf(v0.w);
      hv[4] = (short)f2bf(v1.x); hv[5] = (short)f2bf(v1.y);
      hv[6] = (short)f2bf(v1.z); hv[7] = (short)f2bf(v1.w);
      *(bf16x8*)(l0 + row * 512 + ((kc * 16) ^ ((row & 15) << 4))) = hv;
    }
  }
  bar_lgkm();

  const int lane = tid & 63;
  const int w    = tid >> 6;          // 0..7
  const int ml   = lane & 15;
  const int g    = lane >> 4;         // 0..3
  const int wn0  = w * 32;            // n-offset: 2 tiles of 16 per wave

  const int swz  = ml << 4;                 // row-swizzle ((rf*16+ml)&15 == ml)
  const int bofs = (g * 16) ^ swz;          // k-chunk xor per lane
  char* const hb  = (char*)hbuf;
  const char* const hbr = hb + (size_t)ml * 512;  // B-read base

  mlp_layer(0, hbuf, wt, bias_s, w, lane, ml, g, wn0, swz, bofs);
  mlp_layer(1, hbuf, wt, bias_s, w, lane, ml, g, wn0, swz, bofs);

  // ---- layer 3 + head, fused: h3 stays in registers ----
  {
    const char* wl = (const char*)wt +
        ((size_t)(2 * 16 + w * 2) * 8) * 1024 + lane * 16;

    f32x4 acc[2][8];
    #pragma unroll
    for (int nf = 0; nf < 2; ++nf)
      #pragma unroll
      for (int rf = 0; rf < 8; ++rf)
        acc[nf][rf] = (f32x4){0.f, 0.f, 0.f, 0.f};

    __builtin_amdgcn_s_setprio(1);
    #pragma unroll
    for (int ks = 0; ks < 8; ++ks) {
      bf16x8 a[2];
      #pragma unroll
      for (int nf = 0; nf < 2; ++nf)
        a[nf] = *(const bf16x8*)(wl + (nf * 8 + ks) * 1024);
      #pragma unroll
      for (int rh = 0; rh < 2; ++rh) {
        bf16x8 bq[4];
        #pragma unroll
        for (int rj = 0; rj < 4; ++rj)
          bq[rj] = *(const bf16x8*)(hbr + (rh * 4 + rj) * 8192 + ((ks * 64) ^ bofs));
        #pragma unroll
        for (int nf = 0; nf < 2; ++nf)
          #pragma unroll
          for (int rj = 0; rj < 4; ++rj)
            acc[nf][rh * 4 + rj] = __builtin_amdgcn_mfma_f32_16x16x32_bf16(
                a[nf], bq[rj], acc[nf][rh * 4 + rj], 0, 0, 0);
      }
    }
    __builtin_amdgcn_s_setprio(0);
    bar_only();   // all h2 reads done -> hbuf reusable as reduction pad

    // load wf/bias fragments AFTER the barrier (short liveness, no spill)
    const float* bs = bias_s + 2 * HID;
    const f32x4 bb0 = *(const f32x4*)(bs + wn0 + g * 4);
    const f32x4 bb1 = *(const f32x4*)(bs + wn0 + 16 + g * 4);
    const f32x4 wf0 = *(const f32x4*)(Wf + wn0 + g * 4);
    const f32x4 wf1 = *(const f32x4*)(Wf + wn0 + 16 + g * 4);

    float* pad = (float*)hbuf;   // [128][32] f32 partials, slot-swizzled
    #pragma unroll
    for (int rf = 0; rf < 8; ++rf) {
      const int r = rf * 16 + ml;
      f32x4 x0 = acc[0][rf] + bb0;
      f32x4 x1 = acc[1][rf] + bb1;
      float p = 0.f;
      #pragma unroll
      for (int q = 0; q < 4; ++q) {
        p += fmaxf(x0[q], 0.f) * wf0[q];
        p += fmaxf(x1[q], 0.f) * wf1[q];
      }
      const int slot = (w * 4 + g) ^ ((r & 7) << 2);   // conflict-free banks
      pad[r * 32 + slot] = p;
    }
    bar_lgkm();

    // reduce: 4 threads per row sum 32 partials -> e = exp(logit)
    {
      const int row  = tid >> 2;   // 0..127
      const int part = tid & 3;
      const int sx   = (row & 7) << 2;
      f32x4 v0 = *(const f32x4*)(pad + row * 32 + ((part * 8) ^ sx));
      f32x4 v1 = *(const f32x4*)(pad + row * 32 + ((part * 8 + 4) ^ sx));
      float s = v0[0] + v0[1] + v0[2] + v0[3] + v1[0] + v1[1] + v1[2] + v1[3];
      s += __shfl_xor(s, 1);
      s += __shfl_xor(s, 2);
      if (part == 0)
        out[OUT_P + (size_t)(r0 + row)] = __expf(s + bf_s);
    }
  }
}

// ---- K2: fused segment softmax-denominator + divide + g_emb copy ----
__global__ __launch_bounds__(256) void k_soft(
    const float* __restrict__ g_emb, const int* __restrict__ bidx,
    float* __restrict__ out)
{
  const int b   = blockIdx.x;
  const int tid = threadIdx.x;
  __shared__ float ws[4];
  __shared__ float sden;

  int lo = 0, hi = N_CAND;
  while (lo < hi) { int m = (lo + hi) >> 1; if (bidx[m] < b) lo = m + 1; else hi = m; }
  int lo2 = lo, hi2 = N_CAND;
  while (lo2 < hi2) { int m = (lo2 + hi2) >> 1; if (bidx[m] < b + 1) lo2 = m + 1; else hi2 = m; }

  float s = 0.f;
  for (int i = lo + tid; i < lo2; i += 256) s += out[OUT_P + (size_t)i];
  #pragma unroll
  for (int off = 32; off > 0; off >>= 1) s += __shfl_down(s, off);
  if ((tid & 63) == 0) ws[tid >> 6] = s;
  __syncthreads();
  if (tid == 0) sden = ws[0] + ws[1] + ws[2] + ws[3];
  __syncthreads();
  const float d = sden;
  for (int i = lo + tid; i < lo2; i += 256)
    out[OUT_P + (size_t)i] = out[OUT_P + (size_t)i] / d;

  if (tid < 32) {
    f32x4 v = *(const f32x4*)(g_emb + (size_t)b * EMB + tid * 4);
    *(f32x4*)(out + (size_t)b * EMB + tid * 4) = v;
  }
}

extern "C" void kernel_launch(void* const* d_in, const int* in_sizes, int n_in,
                              void* d_out, int out_size, void* d_ws, size_t ws_size,
                              hipStream_t stream)
{
  const float* g_emb = (const float*)d_in[0];
  const float* cand  = (const float*)d_in[1];
  const float* W1    = (const float*)d_in[2];
  const float* b1    = (const float*)d_in[3];
  const float* W2    = (const float*)d_in[4];
  const float* b2    = (const float*)d_in[5];
  const float* W3    = (const float*)d_in[6];
  const float* b3    = (const float*)d_in[7];
  const float* Wf    = (const float*)d_in[8];
  const float* bfp   = (const float*)d_in[9];
  const int*   bidx  = (const int*)d_in[10];
  float* out = (float*)d_out;

  u16* wt = (u16*)d_ws;    // 3 * 128 KB packed bf16 weights

  k_prep <<<768, 256, 0, stream>>>(W1, W2, W3, wt);
  k_main <<<NBLK, 512, 0, stream>>>(g_emb, cand, bidx, b1, b2, b3, Wf, bfp, wt, out);
  k_soft <<<BGR, 256, 0, stream>>>(g_emb, bidx, out);
}